// Round 3
// baseline (343.812 us; speedup 1.0000x reference)
//
#include <hip/hip_runtime.h>

// ---------------------------------------------------------------------------
// RCLayer softmax: out = softmax_rows( exp(1/(1+||x_i-c_j||^2)) ) (ALPHA=1)
// M=32768, K=512, N=2048, fp32 out [M][N].
// fp8(e4m3) MFMA GEMM for x.c^T fused with row-softmax; ||x||^2/||c||^2 fp32.
// Round 3: 2 blocks/CU co-residency (LDS 75.5KB/block, launch_bounds(512,4))
// so epilogue stores + vmcnt stalls of one block overlap the other's MFMAs.
// Window = one 16KB chunk, 3-buffer pipeline, counted vmcnt(2), final drain 0.
// ---------------------------------------------------------------------------

typedef __attribute__((ext_vector_type(4)))  float        f32x4;
typedef __attribute__((ext_vector_type(16))) float        f32x16;
typedef __attribute__((ext_vector_type(2)))  unsigned int u32x2;

#define AS1 __attribute__((address_space(1)))
#define AS3 __attribute__((address_space(3)))

__device__ __forceinline__ void gl2lds16(const void* g, void* l) {
  // async global->LDS, 16B/lane; LDS dest = uniform base + lane*16
  __builtin_amdgcn_global_load_lds((const AS1 unsigned int*)g,
                                   (AS3 unsigned int*)l, 16, 0, 0);
}
__device__ __forceinline__ float fastrcp(float x) {
  float r; asm("v_rcp_f32 %0, %1" : "=v"(r) : "v"(x)); return r;
}
__device__ __forceinline__ unsigned int pk4_fp8(f32x4 v) {
  unsigned int u = 0;
  u = __builtin_amdgcn_cvt_pk_fp8_f32(v.x, v.y, u, false);
  u = __builtin_amdgcn_cvt_pk_fp8_f32(v.z, v.w, u, true);
  return u;
}

// ---------------------------------------------------------------------------
// Kernel 1: clusters f32[2048][512] -> fp8 chunk image (1MB) + fp32 c2.
// Chunk (kc 0..7, nc 0..7) = cols [nc*256,+256) x k [kc*64,+64) = 16KB at
// offset (kc*8+nc)*16384. Within chunk: [ko 0..7][c 0..255] 8B octets.
// ---------------------------------------------------------------------------
__global__ __launch_bounds__(256) void prep_clusters(
    const float* __restrict__ C, unsigned char* __restrict__ Bws,
    float* __restrict__ c2)
{
  const int t   = blockIdx.x * 256 + threadIdx.x;   // 0..131071
  const int n   = t >> 6;                            // cluster
  const int oct = t & 63;                            // k-octet
  const float* src = C + (size_t)n * 512 + oct * 8;
  f32x4 v0 = *(const f32x4*)src;
  f32x4 v1 = *(const f32x4*)(src + 4);
  float ss = v0.x*v0.x + v0.y*v0.y + v0.z*v0.z + v0.w*v0.w
           + v1.x*v1.x + v1.y*v1.y + v1.z*v1.z + v1.w*v1.w;
  u32x2 h; h.x = pk4_fp8(v0); h.y = pk4_fp8(v1);
  *(u32x2*)(Bws + ((size_t)((oct >> 3) * 8 + (n >> 8)) << 14)
                + ((oct & 7) << 11) + ((size_t)(n & 255) << 3)) = h;
  ss += __shfl_xor(ss, 1);  ss += __shfl_xor(ss, 2);  ss += __shfl_xor(ss, 4);
  ss += __shfl_xor(ss, 8);  ss += __shfl_xor(ss, 16); ss += __shfl_xor(ss, 32);
  if ((threadIdx.x & 63) == 0) c2[n] = ss;
}

// ---------------------------------------------------------------------------
// Kernel 2: fused GEMM + softmax. Block = 32 rows x 2048 cols, 8 waves.
// Window = one chunk (256 cols x 64k): 4 MFMAs/wave. 64 windows.
// ---------------------------------------------------------------------------
__global__ __launch_bounds__(512, 4) void fused_kernel(
    const float* __restrict__ A, const unsigned char* __restrict__ Bws,
    const float* __restrict__ c2, float* __restrict__ out)
{
  __shared__ __align__(16) unsigned char A_sh[64 * 264];   // 16.5KB fp8
  __shared__ __align__(16) unsigned char B_sh[3 * 16384];  // 48KB, 3 bufs
  __shared__ float c2_lds[2048];                           // 8KB
  __shared__ float x2_lds[32];
  __shared__ float wsum[8][32];
  __shared__ float inv_lds[32];

  const int tid  = threadIdx.x;
  const int wave = tid >> 6;
  const int lane = tid & 63;
  const int l31  = lane & 31;
  const int hi   = lane >> 5;
  const int brow = blockIdx.x * 32;

  // ---- c2 -> LDS (epilogue then has no global-latency chain) ----
  {
    f32x4 cv = ((const f32x4*)c2)[tid];
    *(f32x4*)&c2_lds[tid * 4] = cv;
  }
  // ---- A staging: fp32 -> fp8 octet layout in LDS, exact fp32 x2 ----
  {
    const int r   = tid >> 4;        // row 0..31
    const int seg = tid & 15;        // 32-float segment
    const f32x4* ap = (const f32x4*)(A + (size_t)(brow + r) * 512 + seg * 32);
    float ss = 0.f;
#pragma unroll
    for (int i2 = 0; i2 < 4; ++i2) {
      f32x4 va = ap[2 * i2];
      f32x4 vb = ap[2 * i2 + 1];
      ss += va.x*va.x + va.y*va.y + va.z*va.z + va.w*va.w
          + vb.x*vb.x + vb.y*vb.y + vb.z*vb.z + vb.w*vb.w;
      u32x2 h; h.x = pk4_fp8(va); h.y = pk4_fp8(vb);
      *(u32x2*)(A_sh + (seg * 4 + i2) * 264 + r * 8) = h;
    }
    ss += __shfl_xor(ss, 1); ss += __shfl_xor(ss, 2);
    ss += __shfl_xor(ss, 4); ss += __shfl_xor(ss, 8);
    if (seg == 0) x2_lds[r] = ss;
  }
  __syncthreads();

  // ---- per-lane fragment offsets (all lane-consecutive reads) ----
  int off_b[4], off_a[4];
#pragma unroll
  for (int ks = 0; ks < 4; ++ks) {
    off_a[ks] = (ks * 2 + hi) * 264 + l31 * 8;
    off_b[ks] = (ks * 2 + hi) * 2048 + (wave * 32 + l31) * 8;
  }

  f32x16 acc[8];
#pragma unroll
  for (int i = 0; i < 8; ++i)
#pragma unroll
    for (int j = 0; j < 16; ++j) acc[i][j] = 0.f;

  unsigned char* bufA = B_sh;
  unsigned char* bufB = B_sh + 16384;
  unsigned char* bufC = B_sh + 32768;

#define STAGE(itv, dst) {                                                      \
    const unsigned char* g_ = Bws + (size_t)(itv) * 16384                      \
                            + wave * 2048 + lane * 16;                         \
    unsigned char* l_ = (dst) + wave * 2048;                                   \
    gl2lds16(g_, l_);  gl2lds16(g_ + 1024, l_ + 1024); }

  STAGE(0, bufA);
  STAGE(1, bufB);

  for (int kc = 0; kc < 8; ++kc) {
    long af[4];
#pragma unroll
    for (int ks = 0; ks < 4; ++ks)
      af[ks] = *(const long*)(A_sh + kc * (8 * 264) + off_a[ks]);
#pragma unroll
    for (int nc = 0; nc < 8; ++nc) {
      const int it = kc * 8 + nc;
      if (it == 63) {
        asm volatile("s_waitcnt vmcnt(0)" ::: "memory");   // final drain
      } else {
        asm volatile("s_waitcnt vmcnt(2)" ::: "memory");   // chunk `it` landed
      }
      __builtin_amdgcn_sched_barrier(0);
      __builtin_amdgcn_s_barrier();
      asm volatile("" ::: "memory");
      if (it < 62) STAGE(it + 2, bufC);                    // overlaps MFMAs
#pragma unroll
      for (int ks = 0; ks < 4; ++ks) {
        long b0 = *(const long*)(bufA + off_b[ks]);
        acc[nc] = __builtin_amdgcn_mfma_f32_32x32x16_fp8_fp8(af[ks], b0, acc[nc], 0, 0, 0);
      }
      unsigned char* tp = bufA; bufA = bufB; bufB = bufC; bufC = tp;
    }
  }

  // ---- epilogue: d2 -> q -> exp, row-softmax, nt-write ----
  // C/D layout: col = lane&31, row = (r&3) + 8*(r>>2) + 4*hi
  f32x4 x2v[4];
#pragma unroll
  for (int g = 0; g < 4; ++g) x2v[g] = *(const f32x4*)&x2_lds[8 * g + 4 * hi];
  float c2v[8];
#pragma unroll
  for (int nc = 0; nc < 8; ++nc) c2v[nc] = c2_lds[nc * 256 + wave * 32 + l31];

  float p[16];
#pragma unroll
  for (int r = 0; r < 16; ++r) p[r] = 0.f;
#pragma unroll
  for (int nc = 0; nc < 8; ++nc) {
#pragma unroll
    for (int r = 0; r < 16; ++r) {
      float d2 = x2v[r >> 2][r & 3] + c2v[nc] - 2.f * acc[nc][r];
      d2 = fmaxf(d2, 0.f);
      float q = fastrcp(1.f + d2);
      float e = __expf(q);
      acc[nc][r] = e;
      p[r] += e;
    }
  }
#pragma unroll
  for (int r = 0; r < 16; ++r) {
    p[r] += __shfl_xor(p[r], 1);  p[r] += __shfl_xor(p[r], 2);
    p[r] += __shfl_xor(p[r], 4);  p[r] += __shfl_xor(p[r], 8);
    p[r] += __shfl_xor(p[r], 16);
  }
  if (l31 == 0) {
#pragma unroll
    for (int r = 0; r < 16; ++r)
      wsum[wave][(r & 3) + 8 * (r >> 2) + 4 * hi] = p[r];
  }
  __syncthreads();
  if (tid < 32) {
    float t = 0.f;
#pragma unroll
    for (int w = 0; w < 8; ++w) t += wsum[w][tid];
    inv_lds[tid] = fastrcp(t);
  }
  __syncthreads();
  f32x4 invv[4];
#pragma unroll
  for (int g = 0; g < 4; ++g) invv[g] = *(const f32x4*)&inv_lds[8 * g + 4 * hi];

  float* outp = out + (size_t)(brow + 4 * hi) * 2048 + wave * 32 + l31;
#pragma unroll
  for (int nc = 0; nc < 8; ++nc) {
#pragma unroll
    for (int r = 0; r < 16; ++r) {
      const int roff = (r & 3) + 8 * (r >> 2);
      __builtin_nontemporal_store(acc[nc][r] * invv[r >> 2][r & 3],
                                  outp + (size_t)roff * 2048 + nc * 256);
    }
  }
#undef STAGE
}

// ---------------------------------------------------------------------------
extern "C" void kernel_launch(void* const* d_in, const int* in_sizes, int n_in,
                              void* d_out, int out_size, void* d_ws, size_t ws_size,
                              hipStream_t stream) {
  const float* inputs   = (const float*)d_in[0];   // [32768][512] f32
  const float* clusters = (const float*)d_in[1];   // [2048][512] f32
  float* out = (float*)d_out;                      // [32768][2048] f32
  unsigned char* Bws = (unsigned char*)d_ws;               // 1MB fp8 image
  float* c2 = (float*)((char*)d_ws + (1u << 20));          // 8KB fp32
  prep_clusters<<<512, 256, 0, stream>>>(clusters, Bws, c2);
  fused_kernel<<<1024, 512, 0, stream>>>(inputs, Bws, c2, out);
}

// Round 4
// 144.450 us; speedup vs baseline: 2.3802x; 2.3802x over previous
//
#include <hip/hip_runtime.h>

// ---------------------------------------------------------------------------
// RCLayer softmax: out = softmax_rows( exp(1/(1+||x_i-c_j||^2)) ) (ALPHA=1)
// M=32768, K=512, N=2048, fp32 out [M][N].
// fp8(e4m3) MFMA GEMM for x.c^T fused with row-softmax; ||x||^2/||c||^2 fp32.
// Round 4: BARRIER-FREE K-loop. B image reordered [slice][wave][ko][lane] so
// each wave stages exactly the bytes it consumes -> per-wave 4-slot ring
// pipeline, per-wave counted vmcnt(4), no s_barrier in the loop. 2 waves/SIMD
// interleave their stalls instead of lockstepping. A loads non-temporal so
// the 1MB B image stays L2-resident; output stores non-temporal.
// Regs: acc = 128 AGPR + ~96 VGPR => 2 waves/SIMD is the hard cap (r3 lesson:
// never force more via launch_bounds -- it spills acc to scratch).
// ---------------------------------------------------------------------------

typedef __attribute__((ext_vector_type(4)))  float        f32x4;
typedef __attribute__((ext_vector_type(16))) float        f32x16;
typedef __attribute__((ext_vector_type(2)))  unsigned int u32x2;

#define AS1 __attribute__((address_space(1)))
#define AS3 __attribute__((address_space(3)))

__device__ __forceinline__ void gl2lds16(const void* g, void* l) {
  // async global->LDS, 16B/lane; LDS dest = uniform base + lane*16
  __builtin_amdgcn_global_load_lds((const AS1 unsigned int*)g,
                                   (AS3 unsigned int*)l, 16, 0, 0);
}
__device__ __forceinline__ float fastrcp(float x) {
  float r; asm("v_rcp_f32 %0, %1" : "=v"(r) : "v"(x)); return r;
}
__device__ __forceinline__ unsigned int pk4_fp8(f32x4 v) {
  unsigned int u = 0;
  u = __builtin_amdgcn_cvt_pk_fp8_f32(v.x, v.y, u, false);
  u = __builtin_amdgcn_cvt_pk_fp8_f32(v.z, v.w, u, true);
  return u;
}

// ---------------------------------------------------------------------------
// Kernel 1: clusters f32[2048][512] -> fp8 slice image (1MB) + fp32 c2.
// Slice it = kc*8+nc (k-chunk kc 0..7, col-group nc 0..7), 16KB each.
// Within slice: [w 0..7][ko 0..7][l31 0..31] 8B k-octets:
//   off = it*16384 + w*2048 + ko*256 + l31*8
// where col = nc*256 + w*32 + l31, k = kc*64 + ko*8 .. +7.
// ---------------------------------------------------------------------------
__global__ __launch_bounds__(256) void prep_clusters(
    const float* __restrict__ C, unsigned char* __restrict__ Bws,
    float* __restrict__ c2)
{
  const int t   = blockIdx.x * 256 + threadIdx.x;   // 0..131071
  const int n   = t >> 6;                            // cluster (1 wave each)
  const int oct = t & 63;                            // k-octet
  const float* src = C + (size_t)n * 512 + oct * 8;
  f32x4 v0 = *(const f32x4*)src;
  f32x4 v1 = *(const f32x4*)(src + 4);
  float ss = v0.x*v0.x + v0.y*v0.y + v0.z*v0.z + v0.w*v0.w
           + v1.x*v1.x + v1.y*v1.y + v1.z*v1.z + v1.w*v1.w;
  u32x2 h; h.x = pk4_fp8(v0); h.y = pk4_fp8(v1);
  *(u32x2*)(Bws + (size_t)((oct >> 3) * 8 + (n >> 8)) * 16384
                + (size_t)((n >> 5) & 7) * 2048
                + (size_t)(oct & 7) * 256 + (size_t)(n & 31) * 8) = h;
  ss += __shfl_xor(ss, 1);  ss += __shfl_xor(ss, 2);  ss += __shfl_xor(ss, 4);
  ss += __shfl_xor(ss, 8);  ss += __shfl_xor(ss, 16); ss += __shfl_xor(ss, 32);
  if ((threadIdx.x & 63) == 0) c2[n] = ss;
}

// ---------------------------------------------------------------------------
// Kernel 2: fused GEMM + softmax. Block = 32 rows x 2048 cols, 8 waves.
// Per wave: 64 slices (2KB each), ring of 4 LDS slots, vmcnt(4) steady-state,
// 4/2/0 drain on the last three slices. NO barriers in the K-loop.
// ---------------------------------------------------------------------------
__global__ __launch_bounds__(512, 2) void fused_kernel(
    const float* __restrict__ A, const unsigned char* __restrict__ Bws,
    const float* __restrict__ c2, float* __restrict__ out)
{
  __shared__ __align__(16) unsigned char A_sh[64 * 264];   // 16.5KB fp8 (padded)
  __shared__ __align__(16) unsigned char B_sh[8 * 4 * 2048]; // 64KB: 8 waves x 4-slot ring
  __shared__ float x2_lds[32];
  __shared__ float wsum[8][32];
  __shared__ float inv_lds[32];

  const int tid  = threadIdx.x;
  const int wave = tid >> 6;
  const int lane = tid & 63;
  const int l31  = lane & 31;
  const int hi   = lane >> 5;
  const int brow = blockIdx.x * 32;

  // ---- A staging: fp32 -> fp8 octet layout in LDS (nt loads), exact x2 ----
  {
    const int r   = tid >> 4;        // row 0..31
    const int seg = tid & 15;        // 32-float segment
    const f32x4* ap = (const f32x4*)(A + (size_t)(brow + r) * 512 + seg * 32);
    float ss = 0.f;
#pragma unroll
    for (int i2 = 0; i2 < 4; ++i2) {
      f32x4 va = __builtin_nontemporal_load(ap + 2 * i2);
      f32x4 vb = __builtin_nontemporal_load(ap + 2 * i2 + 1);
      ss += va.x*va.x + va.y*va.y + va.z*va.z + va.w*va.w
          + vb.x*vb.x + vb.y*vb.y + vb.z*vb.z + vb.w*vb.w;
      u32x2 h; h.x = pk4_fp8(va); h.y = pk4_fp8(vb);
      *(u32x2*)(A_sh + (seg * 4 + i2) * 264 + r * 8) = h;
    }
    ss += __shfl_xor(ss, 1); ss += __shfl_xor(ss, 2);
    ss += __shfl_xor(ss, 4); ss += __shfl_xor(ss, 8);
    if (seg == 0) x2_lds[r] = ss;
  }

  // ---- per-wave ring + fragment offsets (all lane-consecutive reads) ----
  unsigned char* ring = B_sh + wave * 8192;
  int off_a[4], off_bs[4];
#pragma unroll
  for (int ks = 0; ks < 4; ++ks) {
    off_a[ks]  = (ks * 2 + hi) * 264 + l31 * 8;
    off_bs[ks] = (ks * 2 + hi) * 256 + l31 * 8;
  }

#define STAGE_S(itv) {                                                         \
    const unsigned char* g_ = Bws + (size_t)(itv) * 16384                      \
                            + wave * 2048 + lane * 16;                         \
    unsigned char* l_ = ring + ((itv) & 3) * 2048;                             \
    gl2lds16(g_, l_);  gl2lds16(g_ + 1024, l_ + 1024); }

  STAGE_S(0); STAGE_S(1); STAGE_S(2);

  __syncthreads();   // A_sh / x2_lds ready (B ring is per-wave, no barrier)

  f32x16 acc[8];
#pragma unroll
  for (int i = 0; i < 8; ++i)
#pragma unroll
    for (int j = 0; j < 16; ++j) acc[i][j] = 0.f;

  // ---- main loop: kc 0..6 steady-state ----
  for (int kc = 0; kc < 7; ++kc) {
    long af[4];
#pragma unroll
    for (int ks = 0; ks < 4; ++ks)
      af[ks] = *(const long*)(A_sh + kc * 2112 + off_a[ks]);
#pragma unroll
    for (int nc = 0; nc < 8; ++nc) {
      asm volatile("s_waitcnt vmcnt(4)" ::: "memory");   // slice it landed
      __builtin_amdgcn_sched_barrier(0);
      STAGE_S(kc * 8 + nc + 3);                          // refill ring
      const unsigned char* bp = ring + (nc & 3) * 2048;
#pragma unroll
      for (int ks = 0; ks < 4; ++ks) {
        long b = *(const long*)(bp + off_bs[ks]);
        acc[nc] = __builtin_amdgcn_mfma_f32_32x32x16_fp8_fp8(af[ks], b, acc[nc], 0, 0, 0);
      }
    }
  }
  // ---- tail kc = 7: drain 4/4/4/4/4/4/2/0, stage only while slices remain ----
  {
    long af[4];
#pragma unroll
    for (int ks = 0; ks < 4; ++ks)
      af[ks] = *(const long*)(A_sh + 7 * 2112 + off_a[ks]);
#pragma unroll
    for (int nc = 0; nc < 8; ++nc) {
      if (nc <= 5)      { asm volatile("s_waitcnt vmcnt(4)" ::: "memory"); }
      else if (nc == 6) { asm volatile("s_waitcnt vmcnt(2)" ::: "memory"); }
      else              { asm volatile("s_waitcnt vmcnt(0)" ::: "memory"); }
      __builtin_amdgcn_sched_barrier(0);
      if (nc <= 4) STAGE_S(59 + nc);
      const unsigned char* bp = ring + (nc & 3) * 2048;
#pragma unroll
      for (int ks = 0; ks < 4; ++ks) {
        long b = *(const long*)(bp + off_bs[ks]);
        acc[nc] = __builtin_amdgcn_mfma_f32_32x32x16_fp8_fp8(af[ks], b, acc[nc], 0, 0, 0);
      }
    }
  }

  // ---- epilogue: d2 -> q -> exp, row-softmax, nt-write ----
  // C/D layout: col = lane&31, row = (r&3) + 8*(r>>2) + 4*hi
  f32x4 x2v[4];
#pragma unroll
  for (int g = 0; g < 4; ++g) x2v[g] = *(const f32x4*)&x2_lds[8 * g + 4 * hi];
  float c2v[8];
#pragma unroll
  for (int nc = 0; nc < 8; ++nc) c2v[nc] = c2[nc * 256 + wave * 32 + l31];

  float p[16];
#pragma unroll
  for (int r = 0; r < 16; ++r) p[r] = 0.f;
#pragma unroll
  for (int nc = 0; nc < 8; ++nc) {
#pragma unroll
    for (int r = 0; r < 16; ++r) {
      float d2 = x2v[r >> 2][r & 3] + c2v[nc] - 2.f * acc[nc][r];
      d2 = fmaxf(d2, 0.f);
      float q = fastrcp(1.f + d2);
      float e = __expf(q);
      acc[nc][r] = e;
      p[r] += e;
    }
  }
#pragma unroll
  for (int r = 0; r < 16; ++r) {
    p[r] += __shfl_xor(p[r], 1);  p[r] += __shfl_xor(p[r], 2);
    p[r] += __shfl_xor(p[r], 4);  p[r] += __shfl_xor(p[r], 8);
    p[r] += __shfl_xor(p[r], 16);
  }
  if (l31 == 0) {
#pragma unroll
    for (int r = 0; r < 16; ++r)
      wsum[wave][(r & 3) + 8 * (r >> 2) + 4 * hi] = p[r];
  }
  __syncthreads();
  if (tid < 32) {
    float t = 0.f;
#pragma unroll
    for (int w = 0; w < 8; ++w) t += wsum[w][tid];
    inv_lds[tid] = fastrcp(t);
  }
  __syncthreads();
  f32x4 invv[4];
#pragma unroll
  for (int g = 0; g < 4; ++g) invv[g] = *(const f32x4*)&inv_lds[8 * g + 4 * hi];

  float* outp = out + (size_t)(brow + 4 * hi) * 2048 + wave * 32 + l31;
#pragma unroll
  for (int nc = 0; nc < 8; ++nc) {
#pragma unroll
    for (int r = 0; r < 16; ++r) {
      const int roff = (r & 3) + 8 * (r >> 2);
      __builtin_nontemporal_store(acc[nc][r] * invv[r >> 2][r & 3],
                                  outp + (size_t)roff * 2048 + nc * 256);
    }
  }
#undef STAGE_S
}

// ---------------------------------------------------------------------------
extern "C" void kernel_launch(void* const* d_in, const int* in_sizes, int n_in,
                              void* d_out, int out_size, void* d_ws, size_t ws_size,
                              hipStream_t stream) {
  const float* inputs   = (const float*)d_in[0];   // [32768][512] f32
  const float* clusters = (const float*)d_in[1];   // [2048][512] f32
  float* out = (float*)d_out;                      // [32768][2048] f32
  unsigned char* Bws = (unsigned char*)d_ws;               // 1MB fp8 image
  float* c2 = (float*)((char*)d_ws + (1u << 20));          // 8KB fp32
  prep_clusters<<<512, 256, 0, stream>>>(clusters, Bws, c2);
  fused_kernel<<<1024, 512, 0, stream>>>(inputs, Bws, c2, out);
}